// Round 5
// baseline (466.707 us; speedup 1.0000x reference)
//
#include <hip/hip_runtime.h>
#include <cstdint>
#include <cstddef>

#define N_NODES 8192
#define IN_DIM  256
#define OUT_DIM 64
#define HEADS   2
#define FEAT    128           // OUT_DIM*HEADS
#define NTILES  9             // 144 B-cols: 128 feat + 2 denom + 14 pad
#define ACC_STRIDE 132
#define KSPLIT  8

typedef __bf16 bf16x8 __attribute__((ext_vector_type(8)));
typedef float  f32x4  __attribute__((ext_vector_type(4)));
typedef int    i32x4  __attribute__((ext_vector_type(4)));
typedef unsigned uu32x4 __attribute__((ext_vector_type(4)));

static __device__ __forceinline__ unsigned short f2bf(float f) {
  unsigned u = __float_as_uint(f);
  u += 0x7FFFu + ((u >> 16) & 1u);     // round-to-nearest-even
  return (unsigned short)(u >> 16);
}

// ---------------------------------------------------------------- k_vr
// vr[h][k] = sum_d attn_r[h][d] * W[h*64+d][k]   (2x256)
__global__ void k_vr(const float* __restrict__ W, const float* __restrict__ attn_r,
                     float* __restrict__ vr) {
  const int t = threadIdx.x;               // 512 threads
  const int h = t >> 8, k = t & 255;
  float s = 0.f;
  for (int d = 0; d < OUT_DIM; d++)
    s += attn_r[h*OUT_DIM + d] * W[(size_t)(h*OUT_DIM + d)*IN_DIM + k];
  vr[h*IN_DIM + k] = s;
}

// ---------------------------------------------------------------- k_h
// H = x @ W^T  (fp32, 8192x128). 256 blocks: 64-row x 64-col tiles.
__global__ __launch_bounds__(256) void k_h(const float* __restrict__ x,
                                           const float* __restrict__ W,
                                           float* __restrict__ H) {
  const int rb = blockIdx.x >> 1, cb = blockIdx.x & 1;
  __shared__ float xs[64][68];
  __shared__ float wl[64][68];
  const int tid = threadIdx.x;
  const int ty = tid >> 4, tx = tid & 15;
  float acc[4][4] = {};
  for (int kc = 0; kc < IN_DIM; kc += 64) {
    __syncthreads();
#pragma unroll
    for (int p = 0; p < 4; p++) {
      const int idx = p*256 + tid;
      const int r = idx >> 4, k4 = idx & 15;
      *(float4*)&xs[r][k4*4] = *(const float4*)(x + (size_t)(rb*64 + r)*IN_DIM + kc + k4*4);
      *(float4*)&wl[r][k4*4] = *(const float4*)(W + (size_t)(cb*64 + r)*IN_DIM + kc + k4*4);
    }
    __syncthreads();
#pragma unroll
    for (int k4 = 0; k4 < 16; k4++) {
      float4 xr[4], wr[4];
#pragma unroll
      for (int i = 0; i < 4; i++) {
        xr[i] = *(const float4*)&xs[ty + i*16][k4*4];
        wr[i] = *(const float4*)&wl[tx + i*16][k4*4];
      }
#pragma unroll
      for (int i = 0; i < 4; i++)
#pragma unroll
        for (int j = 0; j < 4; j++)
          acc[i][j] += xr[i].x*wr[j].x + xr[i].y*wr[j].y + xr[i].z*wr[j].z + xr[i].w*wr[j].w;
    }
  }
#pragma unroll
  for (int i = 0; i < 4; i++)
#pragma unroll
    for (int j = 0; j < 4; j++)
      H[(size_t)(rb*64 + ty + i*16)*FEAT + cb*64 + tx + j*16] = acc[i][j];
}

// ---------------------------------------------------------------- k_er
// er[j][h] = dot(x[j,:], vr[h,:])  fp32-exact path feeding exp()
__global__ void k_er(const float* __restrict__ x, const float* __restrict__ vr,
                     float* __restrict__ er) {
  const int wave = threadIdx.x >> 6, lane = threadIdx.x & 63;
  const int j = blockIdx.x*4 + wave;
  float4 xv = ((const float4*)(x + (size_t)j*IN_DIM))[lane];
  float4 a0 = ((const float4*)vr)[lane];
  float4 a1 = ((const float4*)(vr + IN_DIM))[lane];
  float s0 = xv.x*a0.x + xv.y*a0.y + xv.z*a0.z + xv.w*a0.w;
  float s1 = xv.x*a1.x + xv.y*a1.y + xv.z*a1.z + xv.w*a1.w;
#pragma unroll
  for (int off = 32; off > 0; off >>= 1) {
    s0 += __shfl_down(s0, off);
    s1 += __shfl_down(s1, off);
  }
  if (lane == 0) { er[j*2+0] = s0; er[j*2+1] = s1; }
}

// ---------------------------------------------------------------- k_pack
// Fragment-ordered bf16 B: frag[kstep][n][lane][j8]  (kstep = 32 k-rows)
//   lane l holds B[k = kstep*32 + (l>>4)*8 + j][col = n*16 + (l&15)], j in 0..8
__global__ void k_pack(const float* __restrict__ H, const float* __restrict__ er,
                       unsigned short* __restrict__ frag) {
  const int oct = blockIdx.x;          // j-octet, 0..1023
  const int c = threadIdx.x;           // 0..191, active < 144
  if (c >= 144) return;
  const int j0 = oct * 8;
  const int kb = oct >> 2, sub = oct & 3;
  unsigned short v[8];
  if (c < FEAT) {
    const int h = c >> 6;
#pragma unroll
    for (int t = 0; t < 8; t++) {
      float w = __expf(er[(j0 + t)*2 + h]);
      v[t] = f2bf(w * H[(size_t)(j0 + t)*FEAT + c]);
    }
  } else if (c < FEAT + HEADS) {
    const int h = c - FEAT;
#pragma unroll
    for (int t = 0; t < 8; t++) v[t] = f2bf(__expf(er[(j0 + t)*2 + h]));
  } else {
#pragma unroll
    for (int t = 0; t < 8; t++) v[t] = 0;
  }
  uint4 o;
  o.x = (unsigned)v[0] | ((unsigned)v[1] << 16);
  o.y = (unsigned)v[2] | ((unsigned)v[3] << 16);
  o.z = (unsigned)v[4] | ((unsigned)v[5] << 16);
  o.w = (unsigned)v[6] | ((unsigned)v[7] << 16);
  uint4* dst = (uint4*)frag + ((size_t)(kb*NTILES + (c >> 4)))*64 + (sub*16 + (c & 15));
  *dst = o;
}

// ---------------------------------------------------------------- k_bits
// adj int32 -> fragment-ordered bitmask, 8 MB total.
// Output u32 index: row*256 + ks*32 + g*4 + quad; bit t*8+j =
//   adj[row][ks*1024 + (g*4+t)*32 + quad*8 + j] != 0
// One block of 1024 threads per row: reads 32 KB contiguous (coalesced).
__global__ __launch_bounds__(1024) void k_bits(const int* __restrict__ adj,
                                               unsigned* __restrict__ bits) {
  const int row = blockIdx.x, tid = threadIdx.x;   // tid 0..1023
  // thread reads 8 consecutive ints at col = tid*8  (wave = 2 KB contiguous)
  const int* p = adj + (size_t)row*N_NODES + tid*8;
  i32x4 a = *(const i32x4*)p;
  i32x4 b = *(const i32x4*)(p + 4);
  unsigned byte =
      (unsigned)(a.x != 0)       | ((unsigned)(a.y != 0) << 1) |
      ((unsigned)(a.z != 0) << 2) | ((unsigned)(a.w != 0) << 3) |
      ((unsigned)(b.x != 0) << 4) | ((unsigned)(b.y != 0) << 5) |
      ((unsigned)(b.z != 0) << 6) | ((unsigned)(b.w != 0) << 7);
  // col = tid*8 -> quad = tid&3, t = (tid>>2)&3, g = (tid>>4)&7, ks = tid>>7
  // threads tid, tid+4, tid+8, tid+12 hold t=0..3 of the same output word
  unsigned b1 = __shfl_down(byte, 4);
  unsigned b2 = __shfl_down(byte, 8);
  unsigned b3 = __shfl_down(byte, 12);
  if (((tid >> 2) & 3) == 0) {
    unsigned w = byte | (b1 << 8) | (b2 << 16) | (b3 << 24);
    const int ks = tid >> 7, g = (tid >> 4) & 7, quad = tid & 3;
    bits[(size_t)row*256 + ks*32 + g*4 + quad] = w;
  }
}

// ---------------------------------------------------------------- k_main
// accum[ks][8192][132] = adj[:, ks-slice] @ B[ks-slice, 144]  (bf16 MFMA)
// A read as BITS (8 MB total, L2-resident, 16 u32/lane for whole K-slice).
// B fragments from L1/L2, 2-deep register double buffer. No LDS, no barriers.
// Grid 512 = 64 M-blocks (128 rows) x 8 K-splits. 4 waves, 32 rows/wave.
__global__ __launch_bounds__(256, 2) void k_main(const unsigned* __restrict__ bits,
                                                 const uu32x4* __restrict__ fragB,
                                                 float* __restrict__ accum) {
  const int mb = blockIdx.x >> 3;         // 0..63
  const int ks = blockIdx.x & 7;          // 0..7
  const int tid = threadIdx.x;
  const int wave = tid >> 6, lane = tid & 63;
  const int m16 = lane & 15, quad = lane >> 4;

  const int row0 = mb*128 + wave*32 + m16;      // rows row0, row0+16
  const uu32x4* bb = fragB + (size_t)(ks*32)*NTILES*64 + lane;

  // A bits for the whole K-slice: 8 groups x 2 rows
  unsigned wA[8], wB[8];
  {
    const unsigned* pa = bits + (size_t)row0*256 + ks*32 + quad;
    const unsigned* pb = pa + 16*256;
#pragma unroll
    for (int g = 0; g < 8; g++) { wA[g] = pa[g*4]; wB[g] = pb[g*4]; }
  }

  f32x4 acc0[NTILES], acc1[NTILES];
#pragma unroll
  for (int n = 0; n < NTILES; n++) {
    acc0[n] = (f32x4){0.f, 0.f, 0.f, 0.f};
    acc1[n] = (f32x4){0.f, 0.f, 0.f, 0.f};
  }

  uu32x4 Bbuf[2][NTILES];
  auto loadB = [&](int kk, int buf) {
#pragma unroll
    for (int t = 0; t < NTILES; t++)
      Bbuf[buf][t] = bb[(size_t)(kk*NTILES + t)*64];
  };
  auto expand = [&](unsigned m) -> bf16x8 {
    unsigned u0 = ((m & 1u)   ? 0x3F80u : 0u) | ((m & 2u)   ? 0x3F800000u : 0u);
    unsigned u1 = ((m & 4u)   ? 0x3F80u : 0u) | ((m & 8u)   ? 0x3F800000u : 0u);
    unsigned u2 = ((m & 16u)  ? 0x3F80u : 0u) | ((m & 32u)  ? 0x3F800000u : 0u);
    unsigned u3 = ((m & 64u)  ? 0x3F80u : 0u) | ((m & 128u) ? 0x3F800000u : 0u);
    uu32x4 u = {u0, u1, u2, u3};
    return __builtin_bit_cast(bf16x8, u);
  };
  auto compute = [&](int kk, int buf) {
    const int g = kk >> 2, t = kk & 3;
    bf16x8 af0 = expand((wA[g] >> (t*8)) & 0xffu);
    bf16x8 af1 = expand((wB[g] >> (t*8)) & 0xffu);
#pragma unroll
    for (int n = 0; n < NTILES; n++) {
      bf16x8 bfr = __builtin_bit_cast(bf16x8, Bbuf[buf][n]);
      acc0[n] = __builtin_amdgcn_mfma_f32_16x16x32_bf16(af0, bfr, acc0[n], 0, 0, 0);
    }
#pragma unroll
    for (int n = 0; n < NTILES; n++) {
      bf16x8 bfr = __builtin_bit_cast(bf16x8, Bbuf[buf][n]);
      acc1[n] = __builtin_amdgcn_mfma_f32_16x16x32_bf16(af1, bfr, acc1[n], 0, 0, 0);
    }
  };

  loadB(0, 0);
  for (int kk = 0; kk < 32; kk += 2) {
    loadB(kk + 1, 1);
    compute(kk, 0);
    loadB((kk + 2 < 32) ? kk + 2 : 31, 0);   // tail: harmless reload
    compute(kk + 1, 1);
  }

  // epilogue: C/D layout col=lane&15, row=quad*4+reg. Plain stores.
  const int rb0 = mb*128 + wave*32 + quad*4;
  float* op = accum + (size_t)ks*N_NODES*ACC_STRIDE;
#pragma unroll
  for (int n = 0; n < NTILES; n++) {
    if (n == 8 && m16 >= HEADS) continue;  // cols 130..143 are padding
#pragma unroll
    for (int r = 0; r < 4; r++) {
      op[(size_t)(rb0 + r)*ACC_STRIDE + n*16 + m16]      = acc0[n][r];
      op[(size_t)(rb0 + 16 + r)*ACC_STRIDE + n*16 + m16] = acc1[n][r];
    }
  }
}

// ---------------------------------------------------------------- k_div
// out[i][c] = (sum_ks num) / (sum_ks den)
__global__ void k_div(const float* __restrict__ acc, float* __restrict__ out) {
  const int i = blockIdx.x, c = threadIdx.x;   // 8192 x 128
  const int h = c >> 6;
  float num = 0.f, den = 0.f;
#pragma unroll
  for (int s = 0; s < KSPLIT; s++) {
    const float* p = acc + ((size_t)s*N_NODES + i)*ACC_STRIDE;
    num += p[c];
    den += p[FEAT + h];
  }
  out[(size_t)i*FEAT + c] = num / den;
}

// ---------------------------------------------------------------- launch
extern "C" void kernel_launch(void* const* d_in, const int* in_sizes, int n_in,
                              void* d_out, int out_size, void* d_ws, size_t ws_size,
                              hipStream_t stream) {
  const float* x      = (const float*)d_in[0];
  const int*   adj    = (const int*)  d_in[1];
  const float* W      = (const float*)d_in[2];
  // d_in[3] = attn_l: cancels in softmax over j — unused.
  const float* attn_r = (const float*)d_in[4];

  char* ws = (char*)d_ws;
  float* vr            = (float*)(ws + 0);                 // 2 KB
  float* er            = (float*)(ws + 4096);              // 64 KB
  float* H             = (float*)(ws + 131072);            // 4 MB
  unsigned short* frag = (unsigned short*)(ws + 4325376);  // 2.25 MB
  unsigned* bits       = (unsigned*)(ws + 6684672);        // 8 MB
  float* acc           = (float*)(ws + 15073280);          // 8 x 4.33 MB
  float* out           = (float*)d_out;

  hipLaunchKernelGGL(k_vr,   dim3(1),    dim3(512), 0, stream, W, attn_r, vr);
  hipLaunchKernelGGL(k_h,    dim3(256),  dim3(256), 0, stream, x, W, H);
  hipLaunchKernelGGL(k_er,   dim3(2048), dim3(256), 0, stream, x, vr, er);
  hipLaunchKernelGGL(k_pack, dim3(1024), dim3(192), 0, stream, H, er, frag);
  hipLaunchKernelGGL(k_bits, dim3(8192), dim3(1024), 0, stream, adj, bits);
  hipLaunchKernelGGL(k_main, dim3(512),  dim3(256), 0, stream, bits,
                     (const uu32x4*)frag, acc);
  hipLaunchKernelGGL(k_div,  dim3(8192), dim3(128), 0, stream, acc, out);
}

// Round 6
// 431.962 us; speedup vs baseline: 1.0804x; 1.0804x over previous
//
#include <hip/hip_runtime.h>
#include <cstdint>
#include <cstddef>

#define N_NODES 8192
#define IN_DIM  256
#define OUT_DIM 64
#define HEADS   2
#define FEAT    128           // OUT_DIM*HEADS
#define NTILES  9             // 144 B-cols: 128 feat + 2 denom + 14 pad
#define ACC_STRIDE 132
#define KSPLIT  8

typedef __bf16 bf16x8 __attribute__((ext_vector_type(8)));
typedef float  f32x4  __attribute__((ext_vector_type(4)));
typedef int    i32x4  __attribute__((ext_vector_type(4)));
typedef unsigned uu32x4 __attribute__((ext_vector_type(4)));

static __device__ __forceinline__ unsigned short f2bf(float f) {
  unsigned u = __float_as_uint(f);
  u += 0x7FFFu + ((u >> 16) & 1u);     // round-to-nearest-even
  return (unsigned short)(u >> 16);
}

// ---------------------------------------------------------------- k_prep
// Fused: H-tile matmul (registers) + er reduction + exp + bf16 fragment pack.
// 256 blocks; block kb owns source rows j0 = kb*32 .. j0+31, all 128 cols.
// Emits frag[kb][n][lane] (uint4 = 8 bf16, j-octet per lane) — same layout
// k_main consumes: lane l -> col n*16+(l&15), j = (l>>4)*8 + t.
__global__ __launch_bounds__(256) void k_prep(const float* __restrict__ x,
                                              const float* __restrict__ W,
                                              const float* __restrict__ attn_r,
                                              uint4* __restrict__ frag) {
  const int kb = blockIdx.x;                 // 0..255
  const int tid = threadIdx.x;
  const int tx = tid & 15, ty = tid >> 4;    // ty 0..15
  const int j0 = kb * 32;

  __shared__ float xs[32][68];               // [row][k] 8.7 KB
  __shared__ float wl[128][68];              // [col][k] 34.8 KB
  __shared__ unsigned short pk[32][146];     // bf16 pack buffer 9.3 KB

  float acc[2][8] = {};                      // rows ty, ty+16; cols tx+jj*16

  for (int kc = 0; kc < IN_DIM; kc += 64) {
    __syncthreads();
    // stage x-tile: 512 float4 slots, 2 per thread
#pragma unroll
    for (int p = 0; p < 2; p++) {
      const int slot = p*256 + tid;
      const int r = slot >> 4, k4 = slot & 15;
      *(float4*)&xs[r][k4*4] = *(const float4*)(x + (size_t)(j0 + r)*IN_DIM + kc + k4*4);
    }
    // stage W-tile: 2048 float4 slots, 8 per thread
#pragma unroll
    for (int p = 0; p < 8; p++) {
      const int slot = p*256 + tid;
      const int r = slot >> 4, k4 = slot & 15;
      *(float4*)&wl[r][k4*4] = *(const float4*)(W + (size_t)r*IN_DIM + kc + k4*4);
    }
    __syncthreads();
#pragma unroll
    for (int k4 = 0; k4 < 16; k4++) {
      float4 xr[2], wr[8];
#pragma unroll
      for (int i = 0; i < 2; i++) xr[i] = *(const float4*)&xs[ty + i*16][k4*4];
#pragma unroll
      for (int jj = 0; jj < 8; jj++) wr[jj] = *(const float4*)&wl[tx + jj*16][k4*4];
#pragma unroll
      for (int i = 0; i < 2; i++)
#pragma unroll
        for (int jj = 0; jj < 8; jj++)
          acc[i][jj] += xr[i].x*wr[jj].x + xr[i].y*wr[jj].y +
                        xr[i].z*wr[jj].z + xr[i].w*wr[jj].w;
    }
  }

  // er[row][h] = sum_d H[row][h*64+d] * attn_r[h][d]; cols jj<4 -> h0, jj>=4 -> h1
  float ar[8];
#pragma unroll
  for (int jj = 0; jj < 8; jj++)
    ar[jj] = attn_r[((jj >> 2)) * OUT_DIM + ((tx + jj*16) & 63)];
  float e0[2] = {}, e1[2] = {};
#pragma unroll
  for (int i = 0; i < 2; i++) {
#pragma unroll
    for (int jj = 0; jj < 4; jj++) e0[i] += acc[i][jj] * ar[jj];
#pragma unroll
    for (int jj = 4; jj < 8; jj++) e1[i] += acc[i][jj] * ar[jj];
  }
#pragma unroll
  for (int m = 1; m <= 8; m <<= 1) {
#pragma unroll
    for (int i = 0; i < 2; i++) {
      e0[i] += __shfl_xor(e0[i], m);
      e1[i] += __shfl_xor(e1[i], m);
    }
  }
  float w0[2], w1[2];
#pragma unroll
  for (int i = 0; i < 2; i++) { w0[i] = __expf(e0[i]); w1[i] = __expf(e1[i]); }

  // pack: pk[row][col] = bf16(w*H), denom cols 128/129 = bf16(w), 130..143 = 0
#pragma unroll
  for (int i = 0; i < 2; i++) {
    const int row = ty + i*16;
#pragma unroll
    for (int jj = 0; jj < 8; jj++)
      pk[row][tx + jj*16] = f2bf((jj < 4 ? w0[i] : w1[i]) * acc[i][jj]);
    pk[row][128 + tx] = (tx == 0) ? f2bf(w0[i]) : (tx == 1) ? f2bf(w1[i]) : 0;
  }
  __syncthreads();

  // emit 576 uint4 words: word = n*64 + l
#pragma unroll
  for (int t = 0; t < 3; t++) {
    const int wid = t*256 + tid;
    if (wid < 576) {
      const int l = wid & 63, n = wid >> 6;
      const int col = n*16 + (l & 15), jb = (l >> 4) * 8;
      uint4 o;
      o.x = (unsigned)pk[jb+0][col] | ((unsigned)pk[jb+1][col] << 16);
      o.y = (unsigned)pk[jb+2][col] | ((unsigned)pk[jb+3][col] << 16);
      o.z = (unsigned)pk[jb+4][col] | ((unsigned)pk[jb+5][col] << 16);
      o.w = (unsigned)pk[jb+6][col] | ((unsigned)pk[jb+7][col] << 16);
      frag[((size_t)kb*NTILES + n)*64 + l] = o;
    }
  }
}

// ---------------------------------------------------------------- k_main
// accum[ks][8192][132] = adj[:, ks-slice] @ B[ks-slice, 144]  (bf16 MFMA, fp32 acc)
// Barrier-free: no LDS, B fragments read straight from L1/L2, A double-buffered
// in registers. Grid 512 = 64 M-blocks (128 rows) x 8 K-splits. 4 waves/block,
// each wave: 32 rows x 144 cols. Plain stores to per-split slice (no atomics).
__global__ __launch_bounds__(256, 2) void k_main(const int* __restrict__ adj,
                                                 const uint4* __restrict__ fragB,
                                                 float* __restrict__ accum) {
  const int mb = blockIdx.x >> 3;         // 0..63
  const int ks = blockIdx.x & 7;          // 0..7
  const int tid = threadIdx.x;
  const int wave = tid >> 6, lane = tid & 63;
  const int m16 = lane & 15, quad = lane >> 4;

  const int row0 = mb*128 + wave*32 + m16;
  const int* a0 = adj + (size_t)row0*N_NODES + ks*1024 + quad*8;
  const int* a1 = a0 + (size_t)16*N_NODES;
  const uint4* bb = fragB + (size_t)(ks*32)*NTILES*64 + lane;

  f32x4 acc0[NTILES], acc1[NTILES];
#pragma unroll
  for (int n = 0; n < NTILES; n++) {
    acc0[n] = (f32x4){0.f, 0.f, 0.f, 0.f};
    acc1[n] = (f32x4){0.f, 0.f, 0.f, 0.f};
  }

  i32x4  Abuf[2][4];
  uu32x4 Bbuf[2][NTILES];

  auto loadA = [&](int kk, int buf) {
    const i32x4* p0 = (const i32x4*)(a0 + kk*32);
    const i32x4* p1 = (const i32x4*)(a1 + kk*32);
    Abuf[buf][0] = __builtin_nontemporal_load(p0);
    Abuf[buf][1] = __builtin_nontemporal_load(p0 + 1);
    Abuf[buf][2] = __builtin_nontemporal_load(p1);
    Abuf[buf][3] = __builtin_nontemporal_load(p1 + 1);
  };
  auto loadB = [&](int kk, int buf) {
    const uu32x4* b = (const uu32x4*)bb;
#pragma unroll
    for (int t = 0; t < NTILES; t++)
      Bbuf[buf][t] = b[(size_t)(kk*NTILES + t)*64];
  };
  auto conv = [&](const i32x4* A) -> bf16x8 {
    const int* ai = (const int*)A;
    unsigned u0 = (ai[0] ? 0x3F80u : 0u) | (ai[1] ? 0x3F800000u : 0u);
    unsigned u1 = (ai[2] ? 0x3F80u : 0u) | (ai[3] ? 0x3F800000u : 0u);
    unsigned u2 = (ai[4] ? 0x3F80u : 0u) | (ai[5] ? 0x3F800000u : 0u);
    unsigned u3 = (ai[6] ? 0x3F80u : 0u) | (ai[7] ? 0x3F800000u : 0u);
    uu32x4 u = {u0, u1, u2, u3};
    return __builtin_bit_cast(bf16x8, u);
  };
  auto compute = [&](int buf) {
    bf16x8 af0 = conv(&Abuf[buf][0]);
    bf16x8 af1 = conv(&Abuf[buf][2]);
#pragma unroll
    for (int n = 0; n < NTILES; n++) {
      bf16x8 bfr = __builtin_bit_cast(bf16x8, Bbuf[buf][n]);
      acc0[n] = __builtin_amdgcn_mfma_f32_16x16x32_bf16(af0, bfr, acc0[n], 0, 0, 0);
    }
#pragma unroll
    for (int n = 0; n < NTILES; n++) {
      bf16x8 bfr = __builtin_bit_cast(bf16x8, Bbuf[buf][n]);
      acc1[n] = __builtin_amdgcn_mfma_f32_16x16x32_bf16(af1, bfr, acc1[n], 0, 0, 0);
    }
  };

  loadA(0, 0); loadB(0, 0);
  for (int kk = 0; kk < 32; kk += 2) {
    loadA(kk + 1, 1); loadB(kk + 1, 1);
    compute(0);
    const int k2 = (kk + 2 < 32) ? kk + 2 : 31;   // clamp: redundant safe reload at tail
    loadA(k2, 0); loadB(k2, 0);
    compute(1);
  }

  // epilogue: C/D layout col=lane&15, row=quad*4+reg. Plain stores.
  const int rb0 = mb*128 + wave*32 + quad*4;
  float* op = accum + (size_t)ks*N_NODES*ACC_STRIDE;
#pragma unroll
  for (int n = 0; n < NTILES; n++) {
    if (n == 8 && m16 >= HEADS) continue;  // cols 130..143 are padding
#pragma unroll
    for (int r = 0; r < 4; r++) {
      op[(size_t)(rb0 + r)*ACC_STRIDE + n*16 + m16]      = acc0[n][r];
      op[(size_t)(rb0 + 16 + r)*ACC_STRIDE + n*16 + m16] = acc1[n][r];
    }
  }
}

// ---------------------------------------------------------------- k_div
// out[i][c] = (sum_ks num) / (sum_ks den)
__global__ void k_div(const float* __restrict__ acc, float* __restrict__ out) {
  const int i = blockIdx.x, c = threadIdx.x;   // 8192 x 128
  const int h = c >> 6;
  float num = 0.f, den = 0.f;
#pragma unroll
  for (int s = 0; s < KSPLIT; s++) {
    const float* p = acc + ((size_t)s*N_NODES + i)*ACC_STRIDE;
    num += p[c];
    den += p[FEAT + h];
  }
  out[(size_t)i*FEAT + c] = num / den;
}

// ---------------------------------------------------------------- launch
extern "C" void kernel_launch(void* const* d_in, const int* in_sizes, int n_in,
                              void* d_out, int out_size, void* d_ws, size_t ws_size,
                              hipStream_t stream) {
  const float* x      = (const float*)d_in[0];
  const int*   adj    = (const int*)  d_in[1];
  const float* W      = (const float*)d_in[2];
  // d_in[3] = attn_l: cancels in softmax over j — unused.
  const float* attn_r = (const float*)d_in[4];

  char* ws = (char*)d_ws;
  uint4* frag = (uint4*)(ws + 0);              // 2.36 MB
  float* acc  = (float*)(ws + 4194304);        // 8 x 4.33 MB
  float* out  = (float*)d_out;

  hipLaunchKernelGGL(k_prep, dim3(256),  dim3(256), 0, stream, x, W, attn_r, frag);
  hipLaunchKernelGGL(k_main, dim3(512),  dim3(256), 0, stream, adj, frag, acc);
  hipLaunchKernelGGL(k_div,  dim3(8192), dim3(128), 0, stream, acc, out);
}